// Round 18
// baseline (372.089 us; speedup 1.0000x reference)
//
#include <hip/hip_runtime.h>
#include <math.h>

typedef __attribute__((ext_vector_type(8))) __bf16 bf16x8;
typedef __attribute__((ext_vector_type(8))) unsigned short u16x8;
typedef __attribute__((ext_vector_type(4))) unsigned short u16x4;
typedef __attribute__((ext_vector_type(4))) float f32x4;

namespace {
constexpr int EMB = 256;
constexpr int HD  = 128;
constexpr int FF  = 1024;
constexpr float EPSV = 1e-5f;

// fragment-ordered weight regions in ws (ushort elements).
// frag = (nt*KK + kk); elem = (frag*64 + lane)*8 + j  holds
// W^T[nt*16 + (lane&15)][kk*32 + (lane>>4)*8 + j]
constexpr int WS_QKV = 0;        // 24 nt x 8 kk x 512
constexpr int WS_O   = 98304;    // 16 nt x 4 kk x 512
constexpr int WS_1   = 131072;   // 64 nt x 8 kk x 512
constexpr int WS_2   = 393216;   // 16 nt x 32 kk x 512

__device__ __forceinline__ unsigned short f32_to_bf16(float f) {
    return __builtin_bit_cast(unsigned short, (__bf16)f);   // v_cvt RNE
}
__device__ __forceinline__ float bf16_to_f32(unsigned short h) {
    return __builtin_bit_cast(float, ((unsigned int)h) << 16);
}
__device__ __forceinline__ f32x4 mfma16(u16x8 a, u16x8 b, f32x4 c) {
    return __builtin_amdgcn_mfma_f32_16x16x32_bf16(
        __builtin_bit_cast(bf16x8, a), __builtin_bit_cast(bf16x8, b), c, 0, 0, 0);
}
// verified G4 swizzle: bijective within each 8-row stripe, 16B-granular
__device__ __forceinline__ int swzB(int row) { return (row & 7) << 4; }

__device__ __forceinline__ u16x8 ldsA256(const unsigned short* base, int row, int k0) {
    int byte = (row * 256 + k0 * 2) ^ swzB(row);
    return *(const u16x8*)((const char*)base + byte);
}
__device__ __forceinline__ u16x8 ldsA512(const unsigned short* base, int row, int k0) {
    int byte = (row * 512 + k0 * 2) ^ swzB(row);
    return *(const u16x8*)((const char*)base + byte);
}
__device__ __forceinline__ u16x8 ldgF(const unsigned short* base, int frag, int lane) {
    return *(const u16x8*)(base + ((size_t)frag * 64 + lane) * 8);   // 1KB/wave, coalesced
}
} // namespace

// one-shot weight convert: fp32 -> bf16 fragment-ordered layout in ws
__global__ __launch_bounds__(256) void wconv(
    const float* __restrict__ Wq, const float* __restrict__ Wk, const float* __restrict__ Wv,
    const float* __restrict__ Wo, const float* __restrict__ W1, const float* __restrict__ W2,
    unsigned short* __restrict__ ws) {
    int e = blockIdx.x * 256 + threadIdx.x;     // 0..655359
    int j, lane, kk, nt, n, k;
    float v;
    if (e < WS_O) {                             // QKV, K=256, 24 nt
        int t = e; j = t & 7; lane = (t >> 3) & 63; int r2 = t >> 9;
        kk = r2 & 7; nt = r2 >> 3;
        n = nt * 16 + (lane & 15); k = kk * 32 + (lane >> 4) * 8 + j;
        const float* W = (n < 128) ? Wq : ((n < 256) ? Wk : Wv);
        v = W[k * HD + (n & 127)];
    } else if (e < WS_1) {                      // Wo, K=128, 16 nt
        int t = e - WS_O; j = t & 7; lane = (t >> 3) & 63; int r2 = t >> 9;
        kk = r2 & 3; nt = r2 >> 2;
        n = nt * 16 + (lane & 15); k = kk * 32 + (lane >> 4) * 8 + j;
        v = Wo[k * EMB + n];
    } else if (e < WS_2) {                      // W1, K=256, 64 nt
        int t = e - WS_1; j = t & 7; lane = (t >> 3) & 63; int r2 = t >> 9;
        kk = r2 & 7; nt = r2 >> 3;
        n = nt * 16 + (lane & 15); k = kk * 32 + (lane >> 4) * 8 + j;
        v = W1[k * FF + n];
    } else {                                    // W2, K=1024, 16 nt
        int t = e - WS_2; j = t & 7; lane = (t >> 3) & 63; int r2 = t >> 9;
        kk = r2 & 31; nt = r2 >> 5;
        n = nt * 16 + (lane & 15); k = kk * 32 + (lane >> 4) * 8 + j;
        v = W2[k * EMB + n];
    }
    ws[e] = f32_to_bf16(v);
}

// ============ K1: LN1 + QKV + attention + proj + residual -> X1 (d_out, fp32) ============
// one block = 2 sequences (M=64). 8 waves (512 thr), 80KB LDS -> 2 blocks/CU
// (160KB exact) x 8 waves = 4 waves/EU at the 128-reg budget. Phase shapes all
// proven <=~95 live: QKV wave=(mq 0..3, nh 0..1); attention one (seq,head,q)
// per thread (no serial loop), packed-bf16 score cache; X1 afr[4]+bfr[4].
__global__ __launch_bounds__(512, 1) void attn_part(
    const float* __restrict__ X, const float* __restrict__ ln_g, const float* __restrict__ ln_b,
    const float* __restrict__ bq, const float* __restrict__ bk, const float* __restrict__ bv,
    const float* __restrict__ bo, const unsigned short* __restrict__ ws,
    float* __restrict__ x1out) {
    // LDS (80KB): hb [64][256] rb512 @0 (32K) | Qb [64][128] rb256 @32K (16K)
    //             | K @48K (16K) | V @64K (16K)
    __shared__ __attribute__((aligned(16))) char smem[81920];
    unsigned short* hb = (unsigned short*)smem;
    unsigned short* Qb = (unsigned short*)(smem + 32768);
    char* Kc           = smem + 49152;
    char* Vc           = smem + 65536;

    const unsigned short* WTqkv = ws + WS_QKV;
    const unsigned short* WTo   = ws + WS_O;

    const int tid  = threadIdx.x;
    const int wv   = tid >> 6;                  // 0..7
    const int mq   = wv & 3;                    // m-tile (16 rows each, 4 tiles)
    const int nh   = wv >> 2;                   // n-half
    const int lane = tid & 63;
    const int lr   = lane & 15;
    const int lh   = lane >> 4;
    const int row0 = blockIdx.x * 64;
    const f32x4 Z  = {0.f, 0.f, 0.f, 0.f};

    // ---- LN1 from global X -> hb (bf16, swz). 8 thr/row, 64 rows, one pass ----
    {
        const int r = tid >> 3, sub = tid & 7;  // r: 0..63
        const float* xr = X + (size_t)(row0 + r) * EMB;
        float4 vv[8];
        float s = 0.f, ss = 0.f;
        #pragma unroll
        for (int j = 0; j < 8; ++j) {
            float4 v = *(const float4*)&xr[sub * 4 + j * 32];
            vv[j] = v;
            s  += (v.x + v.y) + (v.z + v.w);
            ss += (v.x * v.x + v.y * v.y) + (v.z * v.z + v.w * v.w);
        }
        #pragma unroll
        for (int w = 1; w < 8; w <<= 1) { s += __shfl_xor(s, w, 64); ss += __shfl_xor(ss, w, 64); }
        float mu  = s * (1.f / EMB);
        float inv = rsqrtf(fmaxf(ss * (1.f / EMB) - mu * mu, 0.f) + EPSV);
        #pragma unroll
        for (int j = 0; j < 8; ++j) {
            int c = sub * 4 + j * 32;
            float4 v = vv[j];
            float4 g4 = *(const float4*)&ln_g[c];
            float4 b4 = *(const float4*)&ln_b[c];
            u16x4 pk;
            pk[0] = f32_to_bf16((v.x - mu) * inv * g4.x + b4.x);
            pk[1] = f32_to_bf16((v.y - mu) * inv * g4.y + b4.y);
            pk[2] = f32_to_bf16((v.z - mu) * inv * g4.z + b4.z);
            pk[3] = f32_to_bf16((v.w - mu) * inv * g4.w + b4.w);
            *(u16x4*)((char*)hb + ((r * 512 + c * 2) ^ swzB(r))) = pk;
        }
    }
    __syncthreads();

    // ---- QKV = h @ Wqkv + b.  wave owns (mq, 12 nt of 24); peak ~95 ----
    {
        u16x8 afr[8];
        #pragma unroll
        for (int kk = 0; kk < 8; ++kk)
            afr[kk] = ldsA512(hb, mq * 16 + lr, kk * 32 + lh * 8);
        #pragma unroll 1
        for (int i = 0; i < 12; ++i) {
            int nt = nh * 12 + i;
            u16x8 bfr[8];
            #pragma unroll
            for (int kk = 0; kk < 8; ++kk) bfr[kk] = ldgF(WTqkv, nt * 8 + kk, lane);
            f32x4 e = Z, o = Z;
            #pragma unroll
            for (int kk = 0; kk < 8; kk += 2) {
                e = mfma16(afr[kk], bfr[kk], e);
                o = mfma16(afr[kk + 1], bfr[kk + 1], o);
            }
            f32x4 a = e + o;
            int gcol = nt * 16 + lr;
            int mat = gcol >> 7, c = gcol & 127;
            const float* bias = (mat == 0) ? bq : ((mat == 1) ? bk : bv);
            float bc = bias[c];
            char* regbase = smem + 32768 + mat * 16384;
            #pragma unroll
            for (int reg = 0; reg < 4; ++reg) {
                int r0 = mq * 16 + lh * 4 + reg;
                *(unsigned short*)(regbase + ((r0 * 256 + c * 2) ^ swzB(r0))) =
                    f32_to_bf16(a[reg] + bc);
            }
        }
    }
    __syncthreads();

    // ---- attention (VALU). thread=(seq,head,q), all 512 in one shot ----
    {
        const int sq = tid >> 8;                // 0/1
        const int hd = (tid >> 5) & 7, q = tid & 31;
        const int row = sq * 32 + q;
        int by0 = (row * 256 + hd * 32) ^ swzB(row);
        int by1 = (row * 256 + hd * 32 + 16) ^ swzB(row);
        float qreg[16];
        {
            u16x8 a = *(const u16x8*)((const char*)Qb + by0);
            u16x8 b_ = *(const u16x8*)((const char*)Qb + by1);
            #pragma unroll
            for (int j = 0; j < 8; ++j) { qreg[j] = bf16_to_f32(a[j]); qreg[8 + j] = bf16_to_f32(b_[j]); }
        }
        // pass A: QK^T once; cache scores as packed bf16; masked max of ROUNDED scores
        unsigned int ps[16];
        float mmax = -1e30f;
        #pragma unroll
        for (int k = 0; k < 32; ++k) {
            int rk = sq * 32 + k;
            int kb0 = (rk * 256 + hd * 32) ^ swzB(rk);
            int kb1 = (rk * 256 + hd * 32 + 16) ^ swzB(rk);
            u16x8 a = *(const u16x8*)(Kc + kb0);
            u16x8 b_ = *(const u16x8*)(Kc + kb1);
            float s_ = 0.f;
            #pragma unroll
            for (int j = 0; j < 8; ++j)
                s_ += qreg[j] * bf16_to_f32(a[j]) + qreg[8 + j] * bf16_to_f32(b_[j]);
            s_ *= 0.25f;
            unsigned short us = f32_to_bf16(s_);
            if ((k & 1) == 0) ps[k >> 1] = (unsigned int)us;
            else              ps[k >> 1] |= ((unsigned int)us) << 16;
            if (k <= q) mmax = fmaxf(mmax, bf16_to_f32(us));
        }
        // pass B: unpack scores, accumulate denom + ctx (V reads only)
        float den = 0.f;
        float ctx[16];
        #pragma unroll
        for (int j = 0; j < 16; ++j) ctx[j] = 0.f;
        #pragma unroll
        for (int k = 0; k < 32; ++k) {
            unsigned short us = (unsigned short)((k & 1) ? (ps[k >> 1] >> 16) : (ps[k >> 1] & 0xFFFFu));
            float s_ = bf16_to_f32(us);
            float e = (k <= q) ? __expf(s_ - mmax) : 0.f;
            den += e;
            int rk = sq * 32 + k;
            int kb0 = (rk * 256 + hd * 32) ^ swzB(rk);
            int kb1 = (rk * 256 + hd * 32 + 16) ^ swzB(rk);
            u16x8 va = *(const u16x8*)(Vc + kb0);
            u16x8 vb = *(const u16x8*)(Vc + kb1);
            #pragma unroll
            for (int j = 0; j < 8; ++j) { ctx[j] += e * bf16_to_f32(va[j]); ctx[8 + j] += e * bf16_to_f32(vb[j]); }
        }
        float rd = 1.f / den;
        u16x8 o0, o1;
        #pragma unroll
        for (int j = 0; j < 8; ++j) { o0[j] = f32_to_bf16(ctx[j] * rd); o1[j] = f32_to_bf16(ctx[8 + j] * rd); }
        *(u16x8*)((char*)Qb + by0) = o0;
        *(u16x8*)((char*)Qb + by1) = o1;
    }
    __syncthreads();

    // ---- X1 = ctx @ Wo + bo + X(global) -> x1out fp32.  wave: (mq, 8 nt) ----
    {
        u16x8 afr[4];
        #pragma unroll
        for (int kk = 0; kk < 4; ++kk)
            afr[kk] = ldsA256(Qb, mq * 16 + lr, kk * 32 + lh * 8);
        #pragma unroll 1
        for (int i = 0; i < 8; ++i) {
            int nt = nh * 8 + i;
            u16x8 bfr[4];
            #pragma unroll
            for (int kk = 0; kk < 4; ++kk) bfr[kk] = ldgF(WTo, nt * 4 + kk, lane);
            int col = nt * 16 + lr;
            float bc = bo[col];
            f32x4 e = Z, o = Z;
            e = mfma16(afr[0], bfr[0], e);
            o = mfma16(afr[1], bfr[1], o);
            e = mfma16(afr[2], bfr[2], e);
            o = mfma16(afr[3], bfr[3], o);
            f32x4 a = e + o;
            #pragma unroll
            for (int reg = 0; reg < 4; ++reg) {
                int r0 = mq * 16 + lh * 4 + reg;
                size_t gi = (size_t)(row0 + r0) * EMB + col;
                x1out[gi] = a[reg] + bc + X[gi];
            }
        }
    }
}

// ============ K2: LN2 + FFN + residual, in place on d_out ============
// one block = 64 rows (2 seqs). 8 waves (512 thr), 48KB LDS. W1/W2 read once per
// block. == R15/R17 version verbatim (reproducible: VGPR 64, ~198us, no spill) ==
__global__ __launch_bounds__(512, 1) void ffn_part(
    const float* __restrict__ ln_g, const float* __restrict__ ln_b,
    const float* __restrict__ b1, const float* __restrict__ b2,
    const unsigned short* __restrict__ ws, float* __restrict__ io) {
    // LDS (48KB): h2 [64][256] rb512 @0 (32K) | fch [64][128] rb256 @32K (16K)
    __shared__ __attribute__((aligned(16))) char smem[49152];
    unsigned short* h2  = (unsigned short*)smem;
    unsigned short* fch = (unsigned short*)(smem + 32768);

    const unsigned short* WT1 = ws + WS_1;
    const unsigned short* WT2 = ws + WS_2;

    const int tid  = threadIdx.x;
    const int wv   = tid >> 6;                  // 0..7
    const int lane = tid & 63;
    const int lr   = lane & 15;
    const int lh   = lane >> 4;
    const int row0 = blockIdx.x * 64;
    const f32x4 Z  = {0.f, 0.f, 0.f, 0.f};

    // ---- LN2 from io (X1 fp32) -> h2 (bf16, swz). 8 thr/row, 64 rows, one pass ----
    {
        const int r = tid >> 3, sub = tid & 7;  // r: 0..63
        const float* xr = io + (size_t)(row0 + r) * EMB;
        float4 vv[8];
        float s = 0.f, ss = 0.f;
        #pragma unroll
        for (int j = 0; j < 8; ++j) {
            float4 v = *(const float4*)&xr[sub * 4 + j * 32];
            vv[j] = v;
            s  += (v.x + v.y) + (v.z + v.w);
            ss += (v.x * v.x + v.y * v.y) + (v.z * v.z + v.w * v.w);
        }
        #pragma unroll
        for (int w = 1; w < 8; w <<= 1) { s += __shfl_xor(s, w, 64); ss += __shfl_xor(ss, w, 64); }
        float mu  = s * (1.f / EMB);
        float inv = rsqrtf(fmaxf(ss * (1.f / EMB) - mu * mu, 0.f) + EPSV);
        #pragma unroll
        for (int j = 0; j < 8; ++j) {
            int c = sub * 4 + j * 32;
            float4 v = vv[j];
            float4 g4 = *(const float4*)&ln_g[c];
            float4 b4 = *(const float4*)&ln_b[c];
            u16x4 pk;
            pk[0] = f32_to_bf16((v.x - mu) * inv * g4.x + b4.x);
            pk[1] = f32_to_bf16((v.y - mu) * inv * g4.y + b4.y);
            pk[2] = f32_to_bf16((v.z - mu) * inv * g4.z + b4.z);
            pk[3] = f32_to_bf16((v.w - mu) * inv * g4.w + b4.w);
            *(u16x4*)((char*)h2 + ((r * 512 + c * 2) ^ swzB(r))) = pk;
        }
    }
    __syncthreads();

    // ---- FFN in 8 chunks of 128 FF cols; acc2[4][2] persistent (32 regs) ----
    {
        f32x4 acc2[4][2];
        #pragma unroll
        for (int mt = 0; mt < 4; ++mt) { acc2[mt][0] = Z; acc2[mt][1] = Z; }

        #pragma unroll 1
        for (int ch = 0; ch < 8; ++ch) {
            // FFN1: relu(h2 @ W1[:, chunk] + b1) -> fch. wave owns 1 fn, all 4 mt.
            {
                int fn = ch * 8 + wv;
                u16x8 bAll[8];
                #pragma unroll
                for (int kk = 0; kk < 8; ++kk) bAll[kk] = ldgF(WT1, fn * 8 + kk, lane);
                float bc = b1[fn * 16 + lr];
                int cc = wv * 16 + lr;
                #pragma unroll 1
                for (int mt = 0; mt < 4; ++mt) {
                    u16x8 afr[8];
                    #pragma unroll
                    for (int kk = 0; kk < 8; ++kk)
                        afr[kk] = ldsA512(h2, mt * 16 + lr, kk * 32 + lh * 8);
                    f32x4 e = Z, o = Z;
                    #pragma unroll
                    for (int kk = 0; kk < 8; kk += 2) {
                        e = mfma16(afr[kk], bAll[kk], e);
                        o = mfma16(afr[kk + 1], bAll[kk + 1], o);
                    }
                    f32x4 a = e + o;
                    #pragma unroll
                    for (int reg = 0; reg < 4; ++reg) {
                        int r0 = mt * 16 + lh * 4 + reg;
                        *(unsigned short*)((char*)fch + ((r0 * 256 + cc * 2) ^ swzB(r0))) =
                            f32_to_bf16(fmaxf(a[reg] + bc, 0.f));
                    }
                }
            }
            __syncthreads();
            // FFN2: acc2 += fch @ W2[chunk-slice]. wave owns 2 nt (of 16), all 4 mt.
            #pragma unroll
            for (int i = 0; i < 2; ++i) {
                u16x8 b2f[4];
                #pragma unroll
                for (int kk = 0; kk < 4; ++kk)
                    b2f[kk] = ldgF(WT2, (wv * 2 + i) * 32 + ch * 4 + kk, lane);
                #pragma unroll
                for (int mt = 0; mt < 4; ++mt) {
                    u16x8 afr2[4];
                    #pragma unroll
                    for (int kk = 0; kk < 4; ++kk)
                        afr2[kk] = ldsA256(fch, mt * 16 + lr, kk * 32 + lh * 8);
                    f32x4 t = acc2[mt][i];
                    t = mfma16(afr2[0], b2f[0], t);
                    t = mfma16(afr2[1], b2f[1], t);
                    t = mfma16(afr2[2], b2f[2], t);
                    t = mfma16(afr2[3], b2f[3], t);
                    acc2[mt][i] = t;
                }
            }
            __syncthreads();
        }
        // epilogue: io = acc2 + b2 + X1(io)   (same-thread read-modify-write)
        #pragma unroll
        for (int i = 0; i < 2; ++i) {
            int col = (wv * 2 + i) * 16 + lr;
            float bc = b2[col];
            #pragma unroll
            for (int mt = 0; mt < 4; ++mt) {
                #pragma unroll
                for (int reg = 0; reg < 4; ++reg) {
                    int r0 = mt * 16 + lh * 4 + reg;
                    size_t gi = (size_t)(row0 + r0) * EMB + col;
                    io[gi] = acc2[mt][i][reg] + bc + io[gi];
                }
            }
        }
    }
}

extern "C" void kernel_launch(void* const* d_in, const int* in_sizes, int n_in,
                              void* d_out, int out_size, void* d_ws, size_t ws_size,
                              hipStream_t stream) {
    const float* X    = (const float*)d_in[0];
    const float* ln_g = (const float*)d_in[1];
    const float* ln_b = (const float*)d_in[2];
    const float* Wq   = (const float*)d_in[3];
    const float* bq   = (const float*)d_in[4];
    const float* Wk   = (const float*)d_in[5];
    const float* bk   = (const float*)d_in[6];
    const float* Wv   = (const float*)d_in[7];
    const float* bv   = (const float*)d_in[8];
    const float* Wo   = (const float*)d_in[9];
    const float* bo   = (const float*)d_in[10];
    const float* W1   = (const float*)d_in[11];
    const float* b1   = (const float*)d_in[12];
    const float* W2   = (const float*)d_in[13];
    const float* b2   = (const float*)d_in[14];
    unsigned short* ws = (unsigned short*)d_ws;
    float* O = (float*)d_out;

    wconv<<<2560, 256, 0, stream>>>(Wq, Wk, Wv, Wo, W1, W2, ws);
    attn_part<<<2048, 512, 0, stream>>>(X, ln_g, ln_b, bq, bk, bv, bo, ws, O);
    ffn_part<<<2048, 512, 0, stream>>>(ln_g, ln_b, b1, b2, ws, O);
}

// Round 19
// 345.571 us; speedup vs baseline: 1.0767x; 1.0767x over previous
//
#include <hip/hip_runtime.h>
#include <math.h>

typedef __attribute__((ext_vector_type(8))) __bf16 bf16x8;
typedef __attribute__((ext_vector_type(8))) unsigned short u16x8;
typedef __attribute__((ext_vector_type(4))) unsigned short u16x4;
typedef __attribute__((ext_vector_type(4))) float f32x4;

namespace {
constexpr int EMB = 256;
constexpr int HD  = 128;
constexpr int FF  = 1024;
constexpr float EPSV = 1e-5f;

// fragment-ordered weight regions in ws (ushort elements).
// frag = (nt*KK + kk); elem = (frag*64 + lane)*8 + j  holds
// W^T[nt*16 + (lane&15)][kk*32 + (lane>>4)*8 + j]
constexpr int WS_QKV = 0;        // 24 nt x 8 kk x 512
constexpr int WS_O   = 98304;    // 16 nt x 4 kk x 512
constexpr int WS_1   = 131072;   // 64 nt x 8 kk x 512
constexpr int WS_2   = 393216;   // 16 nt x 32 kk x 512

__device__ __forceinline__ unsigned short f32_to_bf16(float f) {
    return __builtin_bit_cast(unsigned short, (__bf16)f);   // v_cvt RNE
}
__device__ __forceinline__ float bf16_to_f32(unsigned short h) {
    return __builtin_bit_cast(float, ((unsigned int)h) << 16);
}
__device__ __forceinline__ f32x4 mfma16(u16x8 a, u16x8 b, f32x4 c) {
    return __builtin_amdgcn_mfma_f32_16x16x32_bf16(
        __builtin_bit_cast(bf16x8, a), __builtin_bit_cast(bf16x8, b), c, 0, 0, 0);
}
// verified G4 swizzle: bijective within each 8-row stripe, 16B-granular
__device__ __forceinline__ int swzB(int row) { return (row & 7) << 4; }

__device__ __forceinline__ u16x8 ldsA256(const unsigned short* base, int row, int k0) {
    int byte = (row * 256 + k0 * 2) ^ swzB(row);
    return *(const u16x8*)((const char*)base + byte);
}
__device__ __forceinline__ u16x8 ldsA512(const unsigned short* base, int row, int k0) {
    int byte = (row * 512 + k0 * 2) ^ swzB(row);
    return *(const u16x8*)((const char*)base + byte);
}
__device__ __forceinline__ u16x8 ldgF(const unsigned short* base, int frag, int lane) {
    return *(const u16x8*)(base + ((size_t)frag * 64 + lane) * 8);   // 1KB/wave, coalesced
}
} // namespace

// one-shot weight convert: fp32 -> bf16 fragment-ordered layout in ws
__global__ __launch_bounds__(256) void wconv(
    const float* __restrict__ Wq, const float* __restrict__ Wk, const float* __restrict__ Wv,
    const float* __restrict__ Wo, const float* __restrict__ W1, const float* __restrict__ W2,
    unsigned short* __restrict__ ws) {
    int e = blockIdx.x * 256 + threadIdx.x;     // 0..655359
    int j, lane, kk, nt, n, k;
    float v;
    if (e < WS_O) {                             // QKV, K=256, 24 nt
        int t = e; j = t & 7; lane = (t >> 3) & 63; int r2 = t >> 9;
        kk = r2 & 7; nt = r2 >> 3;
        n = nt * 16 + (lane & 15); k = kk * 32 + (lane >> 4) * 8 + j;
        const float* W = (n < 128) ? Wq : ((n < 256) ? Wk : Wv);
        v = W[k * HD + (n & 127)];
    } else if (e < WS_1) {                      // Wo, K=128, 16 nt
        int t = e - WS_O; j = t & 7; lane = (t >> 3) & 63; int r2 = t >> 9;
        kk = r2 & 3; nt = r2 >> 2;
        n = nt * 16 + (lane & 15); k = kk * 32 + (lane >> 4) * 8 + j;
        v = Wo[k * EMB + n];
    } else if (e < WS_2) {                      // W1, K=256, 64 nt
        int t = e - WS_1; j = t & 7; lane = (t >> 3) & 63; int r2 = t >> 9;
        kk = r2 & 7; nt = r2 >> 3;
        n = nt * 16 + (lane & 15); k = kk * 32 + (lane >> 4) * 8 + j;
        v = W1[k * FF + n];
    } else {                                    // W2, K=1024, 16 nt
        int t = e - WS_2; j = t & 7; lane = (t >> 3) & 63; int r2 = t >> 9;
        kk = r2 & 31; nt = r2 >> 5;
        n = nt * 16 + (lane & 15); k = kk * 32 + (lane >> 4) * 8 + j;
        v = W2[k * EMB + n];
    }
    ws[e] = f32_to_bf16(v);
}

// ============ K1: LN1 + QKV + attention + proj + residual -> X1 (d_out, fp32) ============
// one block = 1 sequence (M=32). 4 waves, 40KB LDS. (256,2): 2 waves/EU, 128-reg
// budget. R16 shape + 2-deep STATIC prefetch (bfrA/bfrB) on QKV and X1 B-loads.
__global__ __launch_bounds__(256, 2) void attn_part(
    const float* __restrict__ X, const float* __restrict__ ln_g, const float* __restrict__ ln_b,
    const float* __restrict__ bq, const float* __restrict__ bk, const float* __restrict__ bv,
    const float* __restrict__ bo, const unsigned short* __restrict__ ws,
    float* __restrict__ x1out) {
    // LDS (40KB): hb [32][256] rb512 @0 (16K) | Qb [32][128] rb256 @16K (8K) | K @24K | V @32K
    __shared__ __attribute__((aligned(16))) char smem[40960];
    unsigned short* hb = (unsigned short*)smem;
    unsigned short* Qb = (unsigned short*)(smem + 16384);
    char* Kc           = smem + 24576;
    char* Vc           = smem + 32768;

    const unsigned short* WTqkv = ws + WS_QKV;
    const unsigned short* WTo   = ws + WS_O;

    const int tid  = threadIdx.x;
    const int wv   = tid >> 6;
    const int mh   = wv & 1;                    // m-half (16 rows)
    const int nh   = wv >> 1;                   // n-quarter
    const int lane = tid & 63;
    const int lr   = lane & 15;
    const int lh   = lane >> 4;
    const int row0 = blockIdx.x * 32;
    const f32x4 Z  = {0.f, 0.f, 0.f, 0.f};

    // ---- LN1 from global X -> hb (bf16, swz). 8 thr/row ----
    {
        const int r = tid >> 3, sub = tid & 7;  // r: 0..31
        const float* xr = X + (size_t)(row0 + r) * EMB;
        float4 vv[8];
        float s = 0.f, ss = 0.f;
        #pragma unroll
        for (int j = 0; j < 8; ++j) {
            float4 v = *(const float4*)&xr[sub * 4 + j * 32];
            vv[j] = v;
            s  += (v.x + v.y) + (v.z + v.w);
            ss += (v.x * v.x + v.y * v.y) + (v.z * v.z + v.w * v.w);
        }
        #pragma unroll
        for (int w = 1; w < 8; w <<= 1) { s += __shfl_xor(s, w, 64); ss += __shfl_xor(ss, w, 64); }
        float mu  = s * (1.f / EMB);
        float inv = rsqrtf(fmaxf(ss * (1.f / EMB) - mu * mu, 0.f) + EPSV);
        #pragma unroll
        for (int j = 0; j < 8; ++j) {
            int c = sub * 4 + j * 32;
            float4 v = vv[j];
            float4 g4 = *(const float4*)&ln_g[c];
            float4 b4 = *(const float4*)&ln_b[c];
            u16x4 pk;
            pk[0] = f32_to_bf16((v.x - mu) * inv * g4.x + b4.x);
            pk[1] = f32_to_bf16((v.y - mu) * inv * g4.y + b4.y);
            pk[2] = f32_to_bf16((v.z - mu) * inv * g4.z + b4.z);
            pk[3] = f32_to_bf16((v.w - mu) * inv * g4.w + b4.w);
            *(u16x4*)((char*)hb + ((r * 512 + c * 2) ^ swzB(r))) = pk;
        }
    }
    __syncthreads();

    // ---- QKV = h @ Wqkv + b. wave owns 12 nt x 1 mt; 2-deep static prefetch ----
    {
        u16x8 afr[8];
        #pragma unroll
        for (int kk = 0; kk < 8; ++kk)
            afr[kk] = ldsA512(hb, mh * 16 + lr, kk * 32 + lh * 8);
        u16x8 bfrA[8], bfrB[8];
        #pragma unroll
        for (int kk = 0; kk < 8; ++kk) bfrA[kk] = ldgF(WTqkv, (nh * 12) * 8 + kk, lane);
        #pragma unroll 1
        for (int ii = 0; ii < 6; ++ii) {
            int nt0 = nh * 12 + ii * 2;
            // prefetch odd tile
            #pragma unroll
            for (int kk = 0; kk < 8; ++kk) bfrB[kk] = ldgF(WTqkv, (nt0 + 1) * 8 + kk, lane);
            // compute even tile (bfrA)
            {
                f32x4 e = Z, o = Z;
                #pragma unroll
                for (int kk = 0; kk < 8; kk += 2) {
                    e = mfma16(afr[kk], bfrA[kk], e);
                    o = mfma16(afr[kk + 1], bfrA[kk + 1], o);
                }
                f32x4 a = e + o;
                int gcol = nt0 * 16 + lr;
                int mat = gcol >> 7, c = gcol & 127;
                const float* bias = (mat == 0) ? bq : ((mat == 1) ? bk : bv);
                float bc = bias[c];
                char* regbase = smem + 16384 + mat * 8192;
                #pragma unroll
                for (int reg = 0; reg < 4; ++reg) {
                    int r0 = mh * 16 + lh * 4 + reg;
                    *(unsigned short*)(regbase + ((r0 * 256 + c * 2) ^ swzB(r0))) =
                        f32_to_bf16(a[reg] + bc);
                }
            }
            // prefetch next even tile
            if (ii < 5) {
                #pragma unroll
                for (int kk = 0; kk < 8; ++kk) bfrA[kk] = ldgF(WTqkv, (nt0 + 2) * 8 + kk, lane);
            }
            // compute odd tile (bfrB)
            {
                f32x4 e = Z, o = Z;
                #pragma unroll
                for (int kk = 0; kk < 8; kk += 2) {
                    e = mfma16(afr[kk], bfrB[kk], e);
                    o = mfma16(afr[kk + 1], bfrB[kk + 1], o);
                }
                f32x4 a = e + o;
                int gcol = (nt0 + 1) * 16 + lr;
                int mat = gcol >> 7, c = gcol & 127;
                const float* bias = (mat == 0) ? bq : ((mat == 1) ? bk : bv);
                float bc = bias[c];
                char* regbase = smem + 16384 + mat * 8192;
                #pragma unroll
                for (int reg = 0; reg < 4; ++reg) {
                    int r0 = mh * 16 + lh * 4 + reg;
                    *(unsigned short*)(regbase + ((r0 * 256 + c * 2) ^ swzB(r0))) =
                        f32_to_bf16(a[reg] + bc);
                }
            }
        }
    }
    __syncthreads();

    // ---- attention (VALU). Packed-bf16 score cache: ps[16] uint, static idx ----
    {
        const int hd = tid >> 5, q = tid & 31;
        int by0 = (q * 256 + hd * 32) ^ swzB(q);
        int by1 = (q * 256 + hd * 32 + 16) ^ swzB(q);
        float qreg[16];
        {
            u16x8 a = *(const u16x8*)((const char*)Qb + by0);
            u16x8 b_ = *(const u16x8*)((const char*)Qb + by1);
            #pragma unroll
            for (int j = 0; j < 8; ++j) { qreg[j] = bf16_to_f32(a[j]); qreg[8 + j] = bf16_to_f32(b_[j]); }
        }
        // pass A: QK^T once; cache scores as packed bf16; masked max of ROUNDED scores
        unsigned int ps[16];
        float mmax = -1e30f;
        #pragma unroll
        for (int k = 0; k < 32; ++k) {
            int kb0 = (k * 256 + hd * 32) ^ swzB(k);
            int kb1 = (k * 256 + hd * 32 + 16) ^ swzB(k);
            u16x8 a = *(const u16x8*)(Kc + kb0);
            u16x8 b_ = *(const u16x8*)(Kc + kb1);
            float s_ = 0.f;
            #pragma unroll
            for (int j = 0; j < 8; ++j)
                s_ += qreg[j] * bf16_to_f32(a[j]) + qreg[8 + j] * bf16_to_f32(b_[j]);
            s_ *= 0.25f;
            unsigned short us = f32_to_bf16(s_);
            if ((k & 1) == 0) ps[k >> 1] = (unsigned int)us;
            else              ps[k >> 1] |= ((unsigned int)us) << 16;
            if (k <= q) mmax = fmaxf(mmax, bf16_to_f32(us));
        }
        // pass B: unpack scores, accumulate denom + ctx (V reads only)
        float den = 0.f;
        float ctx[16];
        #pragma unroll
        for (int j = 0; j < 16; ++j) ctx[j] = 0.f;
        #pragma unroll
        for (int k = 0; k < 32; ++k) {
            unsigned short us = (unsigned short)((k & 1) ? (ps[k >> 1] >> 16) : (ps[k >> 1] & 0xFFFFu));
            float s_ = bf16_to_f32(us);
            float e = (k <= q) ? __expf(s_ - mmax) : 0.f;
            den += e;
            int kb0 = (k * 256 + hd * 32) ^ swzB(k);
            int kb1 = (k * 256 + hd * 32 + 16) ^ swzB(k);
            u16x8 va = *(const u16x8*)(Vc + kb0);
            u16x8 vb = *(const u16x8*)(Vc + kb1);
            #pragma unroll
            for (int j = 0; j < 8; ++j) { ctx[j] += e * bf16_to_f32(va[j]); ctx[8 + j] += e * bf16_to_f32(vb[j]); }
        }
        float rd = 1.f / den;
        u16x8 o0, o1;
        #pragma unroll
        for (int j = 0; j < 8; ++j) { o0[j] = f32_to_bf16(ctx[j] * rd); o1[j] = f32_to_bf16(ctx[8 + j] * rd); }
        *(u16x8*)((char*)Qb + by0) = o0;
        *(u16x8*)((char*)Qb + by1) = o1;
    }
    __syncthreads();

    // ---- X1 = ctx @ Wo + bo + X -> x1out fp32. wave: 8 nt x 1 mt; 2-deep prefetch ----
    {
        u16x8 afr[4];
        #pragma unroll
        for (int kk = 0; kk < 4; ++kk)
            afr[kk] = ldsA256(Qb, mh * 16 + lr, kk * 32 + lh * 8);
        u16x8 bfrA[4], bfrB[4];
        #pragma unroll
        for (int kk = 0; kk < 4; ++kk) bfrA[kk] = ldgF(WTo, (nh * 8) * 4 + kk, lane);
        #pragma unroll 1
        for (int ii = 0; ii < 4; ++ii) {
            int nt0 = nh * 8 + ii * 2;
            #pragma unroll
            for (int kk = 0; kk < 4; ++kk) bfrB[kk] = ldgF(WTo, (nt0 + 1) * 4 + kk, lane);
            {
                int col = nt0 * 16 + lr;
                float bc = bo[col];
                f32x4 e = Z, o = Z;
                e = mfma16(afr[0], bfrA[0], e);
                o = mfma16(afr[1], bfrA[1], o);
                e = mfma16(afr[2], bfrA[2], e);
                o = mfma16(afr[3], bfrA[3], o);
                f32x4 a = e + o;
                #pragma unroll
                for (int reg = 0; reg < 4; ++reg) {
                    int r0 = mh * 16 + lh * 4 + reg;
                    size_t gi = (size_t)(row0 + r0) * EMB + col;
                    x1out[gi] = a[reg] + bc + X[gi];
                }
            }
            if (ii < 3) {
                #pragma unroll
                for (int kk = 0; kk < 4; ++kk) bfrA[kk] = ldgF(WTo, (nt0 + 2) * 4 + kk, lane);
            }
            {
                int col = (nt0 + 1) * 16 + lr;
                float bc = bo[col];
                f32x4 e = Z, o = Z;
                e = mfma16(afr[0], bfrB[0], e);
                o = mfma16(afr[1], bfrB[1], o);
                e = mfma16(afr[2], bfrB[2], e);
                o = mfma16(afr[3], bfrB[3], o);
                f32x4 a = e + o;
                #pragma unroll
                for (int reg = 0; reg < 4; ++reg) {
                    int r0 = mh * 16 + lh * 4 + reg;
                    size_t gi = (size_t)(row0 + r0) * EMB + col;
                    x1out[gi] = a[reg] + bc + X[gi];
                }
            }
        }
    }
}

// ============ K2: LN2 + FFN + residual, in place on d_out ============
// one block = 64 rows (2 seqs). 8 waves (512 thr), 48KB LDS. W1/W2 read once per
// block. == R15/R17 version verbatim (reproducible: VGPR 64, ~198us, no spill) ==
__global__ __launch_bounds__(512, 1) void ffn_part(
    const float* __restrict__ ln_g, const float* __restrict__ ln_b,
    const float* __restrict__ b1, const float* __restrict__ b2,
    const unsigned short* __restrict__ ws, float* __restrict__ io) {
    // LDS (48KB): h2 [64][256] rb512 @0 (32K) | fch [64][128] rb256 @32K (16K)
    __shared__ __attribute__((aligned(16))) char smem[49152];
    unsigned short* h2  = (unsigned short*)smem;
    unsigned short* fch = (unsigned short*)(smem + 32768);

    const unsigned short* WT1 = ws + WS_1;
    const unsigned short* WT2 = ws + WS_2;

    const int tid  = threadIdx.x;
    const int wv   = tid >> 6;                  // 0..7
    const int lane = tid & 63;
    const int lr   = lane & 15;
    const int lh   = lane >> 4;
    const int row0 = blockIdx.x * 64;
    const f32x4 Z  = {0.f, 0.f, 0.f, 0.f};

    // ---- LN2 from io (X1 fp32) -> h2 (bf16, swz). 8 thr/row, 64 rows, one pass ----
    {
        const int r = tid >> 3, sub = tid & 7;  // r: 0..63
        const float* xr = io + (size_t)(row0 + r) * EMB;
        float4 vv[8];
        float s = 0.f, ss = 0.f;
        #pragma unroll
        for (int j = 0; j < 8; ++j) {
            float4 v = *(const float4*)&xr[sub * 4 + j * 32];
            vv[j] = v;
            s  += (v.x + v.y) + (v.z + v.w);
            ss += (v.x * v.x + v.y * v.y) + (v.z * v.z + v.w * v.w);
        }
        #pragma unroll
        for (int w = 1; w < 8; w <<= 1) { s += __shfl_xor(s, w, 64); ss += __shfl_xor(ss, w, 64); }
        float mu  = s * (1.f / EMB);
        float inv = rsqrtf(fmaxf(ss * (1.f / EMB) - mu * mu, 0.f) + EPSV);
        #pragma unroll
        for (int j = 0; j < 8; ++j) {
            int c = sub * 4 + j * 32;
            float4 v = vv[j];
            float4 g4 = *(const float4*)&ln_g[c];
            float4 b4 = *(const float4*)&ln_b[c];
            u16x4 pk;
            pk[0] = f32_to_bf16((v.x - mu) * inv * g4.x + b4.x);
            pk[1] = f32_to_bf16((v.y - mu) * inv * g4.y + b4.y);
            pk[2] = f32_to_bf16((v.z - mu) * inv * g4.z + b4.z);
            pk[3] = f32_to_bf16((v.w - mu) * inv * g4.w + b4.w);
            *(u16x4*)((char*)h2 + ((r * 512 + c * 2) ^ swzB(r))) = pk;
        }
    }
    __syncthreads();

    // ---- FFN in 8 chunks of 128 FF cols; acc2[4][2] persistent (32 regs) ----
    {
        f32x4 acc2[4][2];
        #pragma unroll
        for (int mt = 0; mt < 4; ++mt) { acc2[mt][0] = Z; acc2[mt][1] = Z; }

        #pragma unroll 1
        for (int ch = 0; ch < 8; ++ch) {
            // FFN1: relu(h2 @ W1[:, chunk] + b1) -> fch. wave owns 1 fn, all 4 mt.
            {
                int fn = ch * 8 + wv;
                u16x8 bAll[8];
                #pragma unroll
                for (int kk = 0; kk < 8; ++kk) bAll[kk] = ldgF(WT1, fn * 8 + kk, lane);
                float bc = b1[fn * 16 + lr];
                int cc = wv * 16 + lr;
                #pragma unroll 1
                for (int mt = 0; mt < 4; ++mt) {
                    u16x8 afr[8];
                    #pragma unroll
                    for (int kk = 0; kk < 8; ++kk)
                        afr[kk] = ldsA512(h2, mt * 16 + lr, kk * 32 + lh * 8);
                    f32x4 e = Z, o = Z;
                    #pragma unroll
                    for (int kk = 0; kk < 8; kk += 2) {
                        e = mfma16(afr[kk], bAll[kk], e);
                        o = mfma16(afr[kk + 1], bAll[kk + 1], o);
                    }
                    f32x4 a = e + o;
                    #pragma unroll
                    for (int reg = 0; reg < 4; ++reg) {
                        int r0 = mt * 16 + lh * 4 + reg;
                        *(unsigned short*)((char*)fch + ((r0 * 256 + cc * 2) ^ swzB(r0))) =
                            f32_to_bf16(fmaxf(a[reg] + bc, 0.f));
                    }
                }
            }
            __syncthreads();
            // FFN2: acc2 += fch @ W2[chunk-slice]. wave owns 2 nt (of 16), all 4 mt.
            #pragma unroll
            for (int i = 0; i < 2; ++i) {
                u16x8 b2f[4];
                #pragma unroll
                for (int kk = 0; kk < 4; ++kk)
                    b2f[kk] = ldgF(WT2, (wv * 2 + i) * 32 + ch * 4 + kk, lane);
                #pragma unroll
                for (int mt = 0; mt < 4; ++mt) {
                    u16x8 afr2[4];
                    #pragma unroll
                    for (int kk = 0; kk < 4; ++kk)
                        afr2[kk] = ldsA256(fch, mt * 16 + lr, kk * 32 + lh * 8);
                    f32x4 t = acc2[mt][i];
                    t = mfma16(afr2[0], b2f[0], t);
                    t = mfma16(afr2[1], b2f[1], t);
                    t = mfma16(afr2[2], b2f[2], t);
                    t = mfma16(afr2[3], b2f[3], t);
                    acc2[mt][i] = t;
                }
            }
            __syncthreads();
        }
        // epilogue: io = acc2 + b2 + X1(io)   (same-thread read-modify-write)
        #pragma unroll
        for (int i = 0; i < 2; ++i) {
            int col = (wv * 2 + i) * 16 + lr;
            float bc = b2[col];
            #pragma unroll
            for (int mt = 0; mt < 4; ++mt) {
                #pragma unroll
                for (int reg = 0; reg < 4; ++reg) {
                    int r0 = mt * 16 + lh * 4 + reg;
                    size_t gi = (size_t)(row0 + r0) * EMB + col;
                    io[gi] = acc2[mt][i][reg] + bc + io[gi];
                }
            }
        }
    }
}

extern "C" void kernel_launch(void* const* d_in, const int* in_sizes, int n_in,
                              void* d_out, int out_size, void* d_ws, size_t ws_size,
                              hipStream_t stream) {
    const float* X    = (const float*)d_in[0];
    const float* ln_g = (const float*)d_in[1];
    const float* ln_b = (const float*)d_in[2];
    const float* Wq   = (const float*)d_in[3];
    const float* bq   = (const float*)d_in[4];
    const float* Wk   = (const float*)d_in[5];
    const float* bk   = (const float*)d_in[6];
    const float* Wv   = (const float*)d_in[7];
    const float* bv   = (const float*)d_in[8];
    const float* Wo   = (const float*)d_in[9];
    const float* bo   = (const float*)d_in[10];
    const float* W1   = (const float*)d_in[11];
    const float* b1   = (const float*)d_in[12];
    const float* W2   = (const float*)d_in[13];
    const float* b2   = (const float*)d_in[14];
    unsigned short* ws = (unsigned short*)d_ws;
    float* O = (float*)d_out;

    wconv<<<2560, 256, 0, stream>>>(Wq, Wk, Wv, Wo, W1, W2, ws);
    attn_part<<<4096, 256, 0, stream>>>(X, ln_g, ln_b, bq, bk, bv, bo, ws, O);
    ffn_part<<<2048, 512, 0, stream>>>(ln_g, ln_b, b1, b2, ws, O);
}